// Round 1
// 1182.142 us; speedup vs baseline: 1.6679x; 1.6679x over previous
//
#include <hip/hip_runtime.h>
#include <cstdint>
#include <cstddef>

// Experts MoE FFN: y = gelu(x @ w1^T + b1) @ w2^T + b2, 8 experts.
// R2: replace the 128^2 2-barrier GEMM (vmcnt(0) drain per K-step -> 312 TF,
// MfmaUtil 13%) with the 256^2 8-phase counted-vmcnt template:
//   - 256x256 tile, BK=64, 512 thr = 8 waves (2M x 4N), per-wave 128x64 out
//   - LDS 128 KiB: 2 dbuf x (A 32KB + B 32KB), staged via global_load_lds(16B)
//   - per phase: ds_read quadrant frags | 1 half-tile prefetch | s_barrier |
//                setprio(1) 16x MFMA setprio(0) | s_barrier
//   - s_waitcnt vmcnt(4) only at phase 4 of each K-tile (2 half-tiles stay in
//     flight across barriers; never vmcnt(0) in the main loop)
//   - granule swizzle slot = kchunk ^ (row&7), applied to BOTH the pre-swizzled
//     global source (global_load_lds writes linearly) and the ds_read address
//     -> stride-128B fragment reads are bank-conflict-free.

typedef __bf16 bf16;
typedef __attribute__((ext_vector_type(8))) __bf16 bf16x8;
typedef __attribute__((ext_vector_type(4))) __bf16 bf16x4;
typedef __attribute__((ext_vector_type(4))) float floatx4;

#define FENCE() asm volatile("" ::: "memory")
#define BAR() do { FENCE(); __builtin_amdgcn_s_barrier(); FENCE(); } while (0)
#define VMCNT4() asm volatile("s_waitcnt vmcnt(4)" ::: "memory")
#define VMCNT0() asm volatile("s_waitcnt vmcnt(0)" ::: "memory")
#define MFMA16(a, b, c) __builtin_amdgcn_mfma_f32_16x16x32_bf16((a), (b), (c), 0, 0, 0)

// Async global->LDS DMA, 16B/lane. LDS dest is wave-uniform base + lane*16,
// so dest granule indices must be lane-contiguous (g = base + tid is).
__device__ __forceinline__ void async_copy16(void* lds_ptr, const void* g_ptr) {
  __builtin_amdgcn_global_load_lds(
      (const __attribute__((address_space(1))) uint32_t*)g_ptr,
      (__attribute__((address_space(3))) uint32_t*)lds_ptr,
      16, 0, 0);
}

__global__ __launch_bounds__(256) void cvt_f32_to_bf16(
    const float4* __restrict__ src, bf16x4* __restrict__ dst, int n4) {
  int i = blockIdx.x * 256 + threadIdx.x;
  if (i < n4) {
    float4 v = src[i];
    bf16x4 o = {(bf16)v.x, (bf16)v.y, (bf16)v.z, (bf16)v.w};
    dst[i] = o;
  }
}

// Grouped GEMM, A row-major [32768,K], B per-expert [N,K] row-major (B^T path).
// Out[m][n] = sum_k A[m][k]*B[e][n][k] + bias[e][n]; optional exact gelu.
template <int KDIM, int NDIM, bool GELU, typename OutT>
__global__ __launch_bounds__(512, 2) void gemm256_8ph(
    const bf16* __restrict__ A,      // [32768, KDIM]
    const bf16* __restrict__ Bw,     // [8, NDIM, KDIM]
    const float* __restrict__ bias,  // [8, NDIM]
    OutT* __restrict__ Out) {        // [32768, NDIM]
  constexpr int NT = KDIM / 64;          // K-tiles
  constexpr int NB = NDIM / 256;         // n-blocks
  constexpr int NWG = (32768 / 256) * NB;

  // [buf(2)][half(2)][1024 granules] ; granule (r,c): holds k-chunk c^(r&7)
  __shared__ bf16x8 ldsA[4096];  // 64 KB
  __shared__ bf16x8 ldsB[4096];  // 64 KB

  // XCD-aware swizzle (NWG divisible by 8 -> bijective), n-fastest inside.
  const int wgid = ((int)blockIdx.x & 7) * (NWG / 8) + ((int)blockIdx.x >> 3);
  const int n_blk = wgid % NB;
  const int m_blk = wgid / NB;
  const int e = (m_blk >> 2) & 7;        // 4 row-blocks per 1024-token chunk

  const int tid = threadIdx.x;
  const int lane = tid & 63;
  const int wid = tid >> 6;
  const int wm = wid >> 2;               // 0..1 -> rows wm*128..+127
  const int wn = wid & 3;                // 0..3 -> cols wn*64..+63
  const int lo16 = lane & 15;
  const int q = lane >> 4;

  const bf16* Ab = A + (size_t)m_blk * 256 * KDIM;
  const bf16* Bb = Bw + (size_t)e * NDIM * KDIM + (size_t)n_blk * 256 * KDIM;

  // Staging per-thread constants: thread stages granules (i*512+tid), i=0,1.
  // row = h*128 + i*64 + (tid>>3); source k-chunk pre-swizzled by row&7.
  const int srow = tid >> 3;
  const int skoff = ((tid & 7) ^ (srow & 7)) * 8;

  // ds_read swizzled slots: want k-chunk kk*4+q at row (..+lo16).
  const int sl0 = q ^ (lo16 & 7);
  const int sl1 = (4 + q) ^ (lo16 & 7);
  const int aoff = wm * 1024 + lo16 * 8;
  const int boff = wn * 512 + lo16 * 8;

  floatx4 acc[8][4];
#pragma unroll
  for (int i = 0; i < 8; ++i)
#pragma unroll
    for (int j = 0; j < 4; ++j) acc[i][j] = (floatx4)(0.0f);

  bf16x8 afr[4][2];  // current A half-quadrant (reloaded at phase 3)
  bf16x8 bfr[4][2];  // all 4 n-frags kept live across the K-tile

#define STAGE_A(buf, h, kt_) do {                                              \
    const bf16* s_ = Ab + (size_t)((h) * 128 + srow) * KDIM + ((kt_)*64 + skoff); \
    bf16x8* d_ = &ldsA[((buf)*2 + (h)) * 1024 + tid];                          \
    async_copy16(d_, s_);                                                      \
    async_copy16(d_ + 512, s_ + (size_t)64 * KDIM);                            \
  } while (0)
#define STAGE_B(buf, h, kt_) do {                                              \
    const bf16* s_ = Bb + (size_t)((h) * 128 + srow) * KDIM + ((kt_)*64 + skoff); \
    bf16x8* d_ = &ldsB[((buf)*2 + (h)) * 1024 + tid];                          \
    async_copy16(d_, s_);                                                      \
    async_copy16(d_ + 512, s_ + (size_t)64 * KDIM);                            \
  } while (0)

  // Prologue: B(0), A(0), B(1) staged (order matters: vmcnt is in-order).
  STAGE_B(0, 0, 0); STAGE_B(0, 1, 0);
  STAGE_A(0, 0, 0); STAGE_A(0, 1, 0);
  STAGE_B(1, 0, 1); STAGE_B(1, 1, 1);
  VMCNT4();  // A(0),B(0) landed; B(1) may fly
  BAR();

  // Steady-state stage pattern (per tile kt, buffer b=kt&1):
  //   P1: A-lo(kt+1)->b^1   P2: A-hi(kt+1)->b^1
  //   P3: B-lo(kt+2)->b     P4: B-hi(kt+2)->b , then vmcnt(4)
  // Slot-death proof: A halves last read at P3 of their tile; B halves at P2.
  // vmcnt(4) at P4 guarantees A(kt+1)+B(kt+1) arrived before tile kt+1 reads.
  for (int kt = 0; kt < NT; ++kt) {
    const int b = kt & 1;
    const int abase = b * 2048 + aoff;
    const int bbase = b * 2048 + boff;
    const int kA1 = (kt + 1 < NT) ? kt + 1 : NT - 1;  // clamped: dest slot dead,
    const int kB2 = (kt + 2 < NT) ? kt + 2 : NT - 1;  // keeps vmcnt counts uniform

    // ---- phase 1: quadrant (mh0, nh0); 12 ds_reads
#pragma unroll
    for (int i = 0; i < 4; ++i) {
      afr[i][0] = ldsA[abase + i * 128 + sl0];
      afr[i][1] = ldsA[abase + i * 128 + sl1];
    }
#pragma unroll
    for (int j = 0; j < 2; ++j) {
      bfr[j][0] = ldsB[bbase + j * 128 + sl0];
      bfr[j][1] = ldsB[bbase + j * 128 + sl1];
    }
    STAGE_A(b ^ 1, 0, kA1);
    BAR();
    __builtin_amdgcn_s_setprio(1);
#pragma unroll
    for (int i = 0; i < 4; ++i)
#pragma unroll
      for (int j = 0; j < 2; ++j) {
        acc[i][j] = MFMA16(afr[i][0], bfr[j][0], acc[i][j]);
        acc[i][j] = MFMA16(afr[i][1], bfr[j][1], acc[i][j]);
      }
    __builtin_amdgcn_s_setprio(0);
    BAR();

    // ---- phase 2: quadrant (mh0, nh1); 4 ds_reads
#pragma unroll
    for (int j = 2; j < 4; ++j) {
      bfr[j][0] = ldsB[bbase + j * 128 + sl0];
      bfr[j][1] = ldsB[bbase + j * 128 + sl1];
    }
    STAGE_A(b ^ 1, 1, kA1);
    BAR();
    __builtin_amdgcn_s_setprio(1);
#pragma unroll
    for (int i = 0; i < 4; ++i)
#pragma unroll
      for (int j = 2; j < 4; ++j) {
        acc[i][j] = MFMA16(afr[i][0], bfr[j][0], acc[i][j]);
        acc[i][j] = MFMA16(afr[i][1], bfr[j][1], acc[i][j]);
      }
    __builtin_amdgcn_s_setprio(0);
    BAR();

    // ---- phase 3: quadrant (mh1, nh0); 8 ds_reads (afr rows +64)
#pragma unroll
    for (int i = 0; i < 4; ++i) {
      afr[i][0] = ldsA[abase + 512 + i * 128 + sl0];
      afr[i][1] = ldsA[abase + 512 + i * 128 + sl1];
    }
    STAGE_B(b, 0, kB2);
    BAR();
    __builtin_amdgcn_s_setprio(1);
#pragma unroll
    for (int i = 0; i < 4; ++i)
#pragma unroll
      for (int j = 0; j < 2; ++j) {
        acc[4 + i][j] = MFMA16(afr[i][0], bfr[j][0], acc[4 + i][j]);
        acc[4 + i][j] = MFMA16(afr[i][1], bfr[j][1], acc[4 + i][j]);
      }
    __builtin_amdgcn_s_setprio(0);
    BAR();

    // ---- phase 4: quadrant (mh1, nh1); 0 ds_reads; counted vmcnt
    STAGE_B(b, 1, kB2);
    BAR();
    __builtin_amdgcn_s_setprio(1);
#pragma unroll
    for (int i = 0; i < 4; ++i)
#pragma unroll
      for (int j = 2; j < 4; ++j) {
        acc[4 + i][j] = MFMA16(afr[i][0], bfr[j][0], acc[4 + i][j]);
        acc[4 + i][j] = MFMA16(afr[i][1], bfr[j][1], acc[4 + i][j]);
      }
    __builtin_amdgcn_s_setprio(0);
    VMCNT4();  // keep 2 half-tiles in flight; never drain to 0 in the loop
    BAR();
  }
  VMCNT0();  // drain stray tail prefetches before LDS goes out of scope

  // Epilogue. C/D layout: col = lane&15, row = quad*4 + reg (m89/m91).
  const float* be = bias + e * NDIM;
  const size_t row0 = (size_t)m_blk * 256 + (size_t)wm * 128 + q * 4;
  const int col0 = n_blk * 256 + wn * 64 + lo16;
#pragma unroll
  for (int j = 0; j < 4; ++j) {
    const int col = col0 + j * 16;
    const float bv = be[col];
#pragma unroll
    for (int i = 0; i < 8; ++i) {
#pragma unroll
      for (int r = 0; r < 4; ++r) {
        const size_t row = row0 + i * 16 + r;
        float v = acc[i][j][r] + bv;
        if (GELU) v = 0.5f * v * (1.0f + erff(v * 0.70710678118654752f));
        __builtin_nontemporal_store((OutT)v, &Out[row * (size_t)NDIM + col]);
      }
    }
  }
#undef STAGE_A
#undef STAGE_B
}

extern "C" void kernel_launch(void* const* d_in, const int* in_sizes, int n_in,
                              void* d_out, int out_size, void* d_ws, size_t ws_size,
                              hipStream_t stream) {
  const float* x  = (const float*)d_in[0];   // [4,8192,1024]
  const float* w1 = (const float*)d_in[1];   // [8,4096,1024]
  const float* b1 = (const float*)d_in[2];   // [8,4096]
  const float* w2 = (const float*)d_in[3];   // [8,1024,4096]
  const float* b2 = (const float*)d_in[4];   // [8,1024]
  float* out = (float*)d_out;                // [4,8192,1024] fp32
  char* ws = (char*)d_ws;

  // ws layout (448 MiB): xb 64MiB | w1b 64MiB | w2b 64MiB | hb 256MiB
  bf16* xb  = (bf16*)(ws + 0);
  bf16* w1b = (bf16*)(ws + 67108864ull);
  bf16* w2b = (bf16*)(ws + 134217728ull);
  bf16* hb  = (bf16*)(ws + 201326592ull);

  const int n4 = 33554432 / 4;
  dim3 cgrid(n4 / 256), cblk(256);
  cvt_f32_to_bf16<<<cgrid, cblk, 0, stream>>>((const float4*)x,  (bf16x4*)xb,  n4);
  cvt_f32_to_bf16<<<cgrid, cblk, 0, stream>>>((const float4*)w1, (bf16x4*)w1b, n4);
  cvt_f32_to_bf16<<<cgrid, cblk, 0, stream>>>((const float4*)w2, (bf16x4*)w2b, n4);

  // GEMM1: h = gelu(x @ w1^T + b1), K=1024, N=4096, bf16 out. 2048 blocks.
  gemm256_8ph<1024, 4096, true, bf16>
      <<<dim3(2048), dim3(512), 0, stream>>>(xb, w1b, b1, hb);
  // GEMM2: y = h @ w2^T + b2, K=4096, N=1024, fp32 out. 512 blocks.
  gemm256_8ph<4096, 1024, false, float>
      <<<dim3(512), dim3(512), 0, stream>>>(hb, w2b, b2, out);
}